// Round 5
// baseline (95.623 us; speedup 1.0000x reference)
//
#include <hip/hip_runtime.h>
#include <math.h>

#define D 256
#define EPS 1e-8f

__device__ __forceinline__ float dot4(float4 u, float4 v) {
    return u.x*v.x + u.y*v.y + u.z*v.z + u.w*v.w;
}

// loss of one row: logits = {pos, n1, n2} / 0.5, CE with label 0
// fast intrinsics: |err| ~1e-6, threshold is 4.4e-2
__device__ __forceinline__ float row_loss(float pos, float na, float nb) {
    float l0 = pos + pos;   // /T with T=0.5
    float l1 = na + na;
    float l2 = nb + nb;
    float m  = fmaxf(l0, fmaxf(l1, l2));
    float e  = __expf(l0 - m) + __expf(l1 - m) + __expf(l2 - m);
    return __logf(e) - (l0 - m);
}

// Fused single-dispatch kernel. 16 lanes per chunk, one chunk per group
// (2048 blocks x 256 thr / 16 = 32768 groups = n_chunks). Each block writes
// its partial, then the last-arriving block (threadfence ticket) sums all
// partials in fixed index order -> deterministic output, no 2nd dispatch.
__global__ __launch_bounds__(256) void ntxent_fused_kernel(
    const float* __restrict__ zis, const float* __restrict__ zjs,
    int n_chunks, float* __restrict__ partial, unsigned int* __restrict__ counter,
    float* __restrict__ out, float scale, int nb)
{
    const int tid   = blockIdx.x * 256 + threadIdx.x;
    const int lane  = threadIdx.x & 15;          // lane within 16-lane group
    const int group = tid >> 4;

    float local = 0.0f;

    if (group < n_chunks) {
        // reps rows: a = zj row0, b = zj row1, c = zi row0, d = zi row1
        const float4* zi = (const float4*)(zis + (size_t)group * (2 * D));
        const float4* zj = (const float4*)(zjs + (size_t)group * (2 * D));

        // issue all 16 loads before any compute (coalesced: 16 lanes x 16 B
        // = 256 B contiguous per row per group)
        float4 a0 = zj[lane     ], a1 = zj[lane + 16], a2 = zj[lane + 32], a3 = zj[lane + 48];
        float4 b0 = zj[lane + 64], b1 = zj[lane + 80], b2 = zj[lane + 96], b3 = zj[lane +112];
        float4 c0 = zi[lane     ], c1 = zi[lane + 16], c2 = zi[lane + 32], c3 = zi[lane + 48];
        float4 d0 = zi[lane + 64], d1 = zi[lane + 80], d2 = zi[lane + 96], d3 = zi[lane +112];

        float s00 = dot4(a0,a0) + dot4(a1,a1) + dot4(a2,a2) + dot4(a3,a3);
        float s01 = dot4(a0,b0) + dot4(a1,b1) + dot4(a2,b2) + dot4(a3,b3);
        float s02 = dot4(a0,c0) + dot4(a1,c1) + dot4(a2,c2) + dot4(a3,c3);
        float s03 = dot4(a0,d0) + dot4(a1,d1) + dot4(a2,d2) + dot4(a3,d3);
        float s11 = dot4(b0,b0) + dot4(b1,b1) + dot4(b2,b2) + dot4(b3,b3);
        float s12 = dot4(b0,c0) + dot4(b1,c1) + dot4(b2,c2) + dot4(b3,c3);
        float s13 = dot4(b0,d0) + dot4(b1,d1) + dot4(b2,d2) + dot4(b3,d3);
        float s22 = dot4(c0,c0) + dot4(c1,c1) + dot4(c2,c2) + dot4(c3,c3);
        float s23 = dot4(c0,d0) + dot4(c1,d1) + dot4(c2,d2) + dot4(c3,d3);
        float s33 = dot4(d0,d0) + dot4(d1,d1) + dot4(d2,d2) + dot4(d3,d3);

        // butterfly reduce across the 16-lane group; all lanes end with totals
        #pragma unroll
        for (int m = 1; m < 16; m <<= 1) {
            s00 += __shfl_xor(s00, m);
            s11 += __shfl_xor(s11, m);
            s22 += __shfl_xor(s22, m);
            s33 += __shfl_xor(s33, m);
            s01 += __shfl_xor(s01, m);
            s02 += __shfl_xor(s02, m);
            s03 += __shfl_xor(s03, m);
            s12 += __shfl_xor(s12, m);
            s13 += __shfl_xor(s13, m);
            s23 += __shfl_xor(s23, m);
        }

        // lanes 0..3 of each group each compute one row's loss (NEG_IDX):
        //   row0: pos=v02 negs v01,v03 | row1: pos=v13 negs v01,v12
        //   row2: pos=v02 negs v12,v23 | row3: pos=v13 negs v03,v23
        float rl = 0.0f;
        if (lane < 4) {
            const int r = lane;
            float i0 = __frsqrt_rn(fmaxf(s00, EPS*EPS));
            float i1 = __frsqrt_rn(fmaxf(s11, EPS*EPS));
            float i2 = __frsqrt_rn(fmaxf(s22, EPS*EPS));
            float i3 = __frsqrt_rn(fmaxf(s33, EPS*EPS));
            float v01 = s01 * i0 * i1;
            float v02 = s02 * i0 * i2;
            float v03 = s03 * i0 * i3;
            float v12 = s12 * i1 * i2;
            float v13 = s13 * i1 * i3;
            float v23 = s23 * i2 * i3;
            float pos = (r & 1) ? v13 : v02;
            float na  = (r < 2) ? v01 : ((r == 2) ? v12 : v03);
            float nb_ = (r == 0) ? v03 : ((r == 1) ? v12 : v23);
            rl = row_loss(pos, na, nb_);
        }
        // fold the 4 row losses (stays within lanes 0-3 of the group)
        rl += __shfl_xor(rl, 1);
        rl += __shfl_xor(rl, 2);
        if (lane == 0) local = rl;
    }

    // block reduction: wave64 butterfly, then tiny LDS combine
    #pragma unroll
    for (int m = 1; m < 64; m <<= 1) local += __shfl_xor(local, m);
    __shared__ float red[4];
    if ((threadIdx.x & 63) == 0) red[threadIdx.x >> 6] = local;
    __syncthreads();

    // ---- last-block ticket reduction (deterministic: fixed summation order)
    __shared__ unsigned int sticket;
    if (threadIdx.x == 0) {
        partial[blockIdx.x] = red[0] + red[1] + red[2] + red[3];
        __threadfence();                       // device-scope release (cross-XCD)
        sticket = atomicAdd(counter, 1u);      // device-scope by default
    }
    __syncthreads();
    if (sticket == (unsigned int)(nb - 1)) {
        float v = 0.0f;
        for (int i = threadIdx.x; i < nb; i += 256) v += partial[i];
        #pragma unroll
        for (int m = 1; m < 64; m <<= 1) v += __shfl_xor(v, m);
        __shared__ float red2[4];
        if ((threadIdx.x & 63) == 0) red2[threadIdx.x >> 6] = v;
        __syncthreads();
        if (threadIdx.x == 0)
            out[0] = (red2[0] + red2[1] + red2[2] + red2[3]) * scale;
    }
}

extern "C" void kernel_launch(void* const* d_in, const int* in_sizes, int n_in,
                              void* d_out, int out_size, void* d_ws, size_t ws_size,
                              hipStream_t stream) {
    const float* zis = (const float*)d_in[0];
    const float* zjs = (const float*)d_in[1];
    float* out       = (float*)d_out;

    // ws layout: [0..3] ticket counter (own cache line), partials at +256 B
    unsigned int* counter = (unsigned int*)d_ws;
    float* partial        = (float*)((char*)d_ws + 256);

    const int B        = in_sizes[0] / D;   // 65536 rows
    const int n_chunks = B / 2;             // 32768 chunks

    int nb = (n_chunks * 16 + 255) / 256;   // 2048 blocks: one 16-lane group per chunk
    size_t cap = (ws_size > 256) ? (ws_size - 256) / sizeof(float) : 1;
    if (cap < (size_t)nb) nb = (int)(cap > 0 ? cap : 1);

    // zero the ticket counter each call (graph-capturable memset node)
    hipMemsetAsync(d_ws, 0, 256, stream);

    ntxent_fused_kernel<<<nb, 256, 0, stream>>>(zis, zjs, n_chunks, partial,
                                                counter, out, 1.0f / (float)B, nb);
}

// Round 6
// 42.369 us; speedup vs baseline: 2.2569x; 2.2569x over previous
//
#include <hip/hip_runtime.h>
#include <math.h>

#define D 256
#define EPS 1e-8f
#define FIXED_SCALE 268435456.0   // 2^28

__device__ __forceinline__ float dot4(float4 u, float4 v) {
    return u.x*v.x + u.y*v.y + u.z*v.z + u.w*v.w;
}

// loss of one row: logits = {pos, n1, n2} / 0.5, CE with label 0
// fast intrinsics: |err| ~1e-6, threshold is 4.4e-2
__device__ __forceinline__ float row_loss(float pos, float na, float nb) {
    float l0 = pos + pos;   // /T with T=0.5
    float l1 = na + na;
    float l2 = nb + nb;
    float m  = fmaxf(l0, fmaxf(l1, l2));
    float e  = __expf(l0 - m) + __expf(l1 - m) + __expf(l2 - m);
    return __logf(e) - (l0 - m);
}

// Single-dispatch fused kernel. 16 lanes per chunk, one chunk per group
// (2048 blocks x 256 thr / 16 = 32768 groups = n_chunks).
// Cross-block combine: one u64 atomicAdd per block of (fixed<<12 | 1).
//  - upper bits: block loss in 2^28 fixed point (integer add = order-
//    independent => bit-deterministic)
//  - low 12 bits: arrival count; the block seeing old_count == nb-1 holds
//    everyone else's sum in `old` and writes the output.
// No __threadfence (R5 post-mortem: device-scope release fence per block
// forces L2 writeback on non-coherent XCD L2s, 3x slowdown). All cross-block
// communication goes through the coherent-point atomic itself.
__global__ __launch_bounds__(256) void ntxent_fused_kernel(
    const float* __restrict__ zis, const float* __restrict__ zjs,
    int n_chunks, unsigned long long* __restrict__ acc,
    float* __restrict__ out, float scale, int nb)
{
    const int tid   = blockIdx.x * 256 + threadIdx.x;
    const int lane  = threadIdx.x & 15;          // lane within 16-lane group
    const int group = tid >> 4;

    float local = 0.0f;

    if (group < n_chunks) {
        // reps rows: a = zj row0, b = zj row1, c = zi row0, d = zi row1
        const float4* zi = (const float4*)(zis + (size_t)group * (2 * D));
        const float4* zj = (const float4*)(zjs + (size_t)group * (2 * D));

        // issue all 16 loads before any compute (coalesced: 16 lanes x 16 B
        // = 256 B contiguous per row per group)
        float4 a0 = zj[lane     ], a1 = zj[lane + 16], a2 = zj[lane + 32], a3 = zj[lane + 48];
        float4 b0 = zj[lane + 64], b1 = zj[lane + 80], b2 = zj[lane + 96], b3 = zj[lane +112];
        float4 c0 = zi[lane     ], c1 = zi[lane + 16], c2 = zi[lane + 32], c3 = zi[lane + 48];
        float4 d0 = zi[lane + 64], d1 = zi[lane + 80], d2 = zi[lane + 96], d3 = zi[lane +112];

        float s00 = dot4(a0,a0) + dot4(a1,a1) + dot4(a2,a2) + dot4(a3,a3);
        float s01 = dot4(a0,b0) + dot4(a1,b1) + dot4(a2,b2) + dot4(a3,b3);
        float s02 = dot4(a0,c0) + dot4(a1,c1) + dot4(a2,c2) + dot4(a3,c3);
        float s03 = dot4(a0,d0) + dot4(a1,d1) + dot4(a2,d2) + dot4(a3,d3);
        float s11 = dot4(b0,b0) + dot4(b1,b1) + dot4(b2,b2) + dot4(b3,b3);
        float s12 = dot4(b0,c0) + dot4(b1,c1) + dot4(b2,c2) + dot4(b3,c3);
        float s13 = dot4(b0,d0) + dot4(b1,d1) + dot4(b2,d2) + dot4(b3,d3);
        float s22 = dot4(c0,c0) + dot4(c1,c1) + dot4(c2,c2) + dot4(c3,c3);
        float s23 = dot4(c0,d0) + dot4(c1,d1) + dot4(c2,d2) + dot4(c3,d3);
        float s33 = dot4(d0,d0) + dot4(d1,d1) + dot4(d2,d2) + dot4(d3,d3);

        // butterfly reduce across the 16-lane group; all lanes end with totals
        #pragma unroll
        for (int m = 1; m < 16; m <<= 1) {
            s00 += __shfl_xor(s00, m);
            s11 += __shfl_xor(s11, m);
            s22 += __shfl_xor(s22, m);
            s33 += __shfl_xor(s33, m);
            s01 += __shfl_xor(s01, m);
            s02 += __shfl_xor(s02, m);
            s03 += __shfl_xor(s03, m);
            s12 += __shfl_xor(s12, m);
            s13 += __shfl_xor(s13, m);
            s23 += __shfl_xor(s23, m);
        }

        // lanes 0..3 of each group each compute one row's loss (NEG_IDX):
        //   row0: pos=v02 negs v01,v03 | row1: pos=v13 negs v01,v12
        //   row2: pos=v02 negs v12,v23 | row3: pos=v13 negs v03,v23
        float rl = 0.0f;
        if (lane < 4) {
            const int r = lane;
            float i0 = __frsqrt_rn(fmaxf(s00, EPS*EPS));
            float i1 = __frsqrt_rn(fmaxf(s11, EPS*EPS));
            float i2 = __frsqrt_rn(fmaxf(s22, EPS*EPS));
            float i3 = __frsqrt_rn(fmaxf(s33, EPS*EPS));
            float v01 = s01 * i0 * i1;
            float v02 = s02 * i0 * i2;
            float v03 = s03 * i0 * i3;
            float v12 = s12 * i1 * i2;
            float v13 = s13 * i1 * i3;
            float v23 = s23 * i2 * i3;
            float pos = (r & 1) ? v13 : v02;
            float na  = (r < 2) ? v01 : ((r == 2) ? v12 : v03);
            float nb_ = (r == 0) ? v03 : ((r == 1) ? v12 : v23);
            rl = row_loss(pos, na, nb_);
        }
        // fold the 4 row losses (stays within lanes 0-3 of the group)
        rl += __shfl_xor(rl, 1);
        rl += __shfl_xor(rl, 2);
        if (lane == 0) local = rl;
    }

    // block reduction: wave64 butterfly, then tiny LDS combine
    #pragma unroll
    for (int m = 1; m < 64; m <<= 1) local += __shfl_xor(local, m);
    __shared__ float red[4];
    if ((threadIdx.x & 63) == 0) red[threadIdx.x >> 6] = local;
    __syncthreads();

    if (threadIdx.x == 0) {
        float part = red[0] + red[1] + red[2] + red[3];   // block partial, >= 0
        unsigned long long fixed =
            (unsigned long long)((double)part * FIXED_SCALE);
        unsigned long long old = atomicAdd(acc, (fixed << 12) | 1ull);
        if ((old & 0xFFFull) == (unsigned long long)(nb - 1)) {
            // all other blocks' contributions are already in `old`
            unsigned long long total = (old >> 12) + fixed;
            out[0] = (float)((double)total * (1.0 / FIXED_SCALE) * (double)scale);
        }
    }
}

extern "C" void kernel_launch(void* const* d_in, const int* in_sizes, int n_in,
                              void* d_out, int out_size, void* d_ws, size_t ws_size,
                              hipStream_t stream) {
    const float* zis = (const float*)d_in[0];
    const float* zjs = (const float*)d_in[1];
    float* out       = (float*)d_out;
    unsigned long long* acc = (unsigned long long*)d_ws;

    const int B        = in_sizes[0] / D;   // 65536 rows
    const int n_chunks = B / 2;             // 32768 chunks

    int nb = (n_chunks * 16 + 255) / 256;   // 2048 blocks (< 4096: fits 12-bit count)

    // zero the packed accumulator each call (graph-capturable memset node)
    hipMemsetAsync(d_ws, 0, sizeof(unsigned long long), stream);

    ntxent_fused_kernel<<<nb, 256, 0, stream>>>(zis, zjs, n_chunks, acc, out,
                                                1.0f / (float)B, nb);
}

// Round 7
// 28.204 us; speedup vs baseline: 3.3904x; 1.5022x over previous
//
#include <hip/hip_runtime.h>
#include <math.h>

#define D 256
#define EPS 1e-8f

__device__ __forceinline__ float dot4(float4 u, float4 v) {
    return u.x*v.x + u.y*v.y + u.z*v.z + u.w*v.w;
}

// loss of one row: logits = {pos, n1, n2} / 0.5, CE with label 0
// fast intrinsics: |err| ~1e-6, threshold is 4.4e-2
__device__ __forceinline__ float row_loss(float pos, float na, float nb) {
    float l0 = pos + pos;   // /T with T=0.5
    float l1 = na + na;
    float l2 = nb + nb;
    float m  = fmaxf(l0, fmaxf(l1, l2));
    float e  = __expf(l0 - m) + __expf(l1 - m) + __expf(l2 - m);
    return __logf(e) - (l0 - m);
}

// 16 lanes per chunk, one chunk per group (2048 blocks x 256 thr / 16 = 32768
// groups = n_chunks). All 16 float4 loads issued upfront into named registers.
// Two-dispatch reduction: measured cheaper than any cross-block sync on this
// chip (R5: __threadfence ticket +115us from per-block L2 writeback across
// non-coherent XCD L2s; R6: packed same-address atomic +14us from atomic
// serialization tail + memset graph node).
__global__ __launch_bounds__(256) void ntxent_partial_kernel(
    const float* __restrict__ zis, const float* __restrict__ zjs,
    int n_chunks, float* __restrict__ partial, float scale)
{
    const int tid   = blockIdx.x * 256 + threadIdx.x;
    const int lane  = threadIdx.x & 15;          // lane within 16-lane group
    const int group = tid >> 4;

    float local = 0.0f;

    if (group < n_chunks) {
        // reps rows: a = zj row0, b = zj row1, c = zi row0, d = zi row1
        const float4* zi = (const float4*)(zis + (size_t)group * (2 * D));
        const float4* zj = (const float4*)(zjs + (size_t)group * (2 * D));

        // issue all 16 loads before any compute (coalesced: 16 lanes x 16 B
        // = 256 B contiguous per row per group)
        float4 a0 = zj[lane     ], a1 = zj[lane + 16], a2 = zj[lane + 32], a3 = zj[lane + 48];
        float4 b0 = zj[lane + 64], b1 = zj[lane + 80], b2 = zj[lane + 96], b3 = zj[lane +112];
        float4 c0 = zi[lane     ], c1 = zi[lane + 16], c2 = zi[lane + 32], c3 = zi[lane + 48];
        float4 d0 = zi[lane + 64], d1 = zi[lane + 80], d2 = zi[lane + 96], d3 = zi[lane +112];

        float s00 = dot4(a0,a0) + dot4(a1,a1) + dot4(a2,a2) + dot4(a3,a3);
        float s01 = dot4(a0,b0) + dot4(a1,b1) + dot4(a2,b2) + dot4(a3,b3);
        float s02 = dot4(a0,c0) + dot4(a1,c1) + dot4(a2,c2) + dot4(a3,c3);
        float s03 = dot4(a0,d0) + dot4(a1,d1) + dot4(a2,d2) + dot4(a3,d3);
        float s11 = dot4(b0,b0) + dot4(b1,b1) + dot4(b2,b2) + dot4(b3,b3);
        float s12 = dot4(b0,c0) + dot4(b1,c1) + dot4(b2,c2) + dot4(b3,c3);
        float s13 = dot4(b0,d0) + dot4(b1,d1) + dot4(b2,d2) + dot4(b3,d3);
        float s22 = dot4(c0,c0) + dot4(c1,c1) + dot4(c2,c2) + dot4(c3,c3);
        float s23 = dot4(c0,d0) + dot4(c1,d1) + dot4(c2,d2) + dot4(c3,d3);
        float s33 = dot4(d0,d0) + dot4(d1,d1) + dot4(d2,d2) + dot4(d3,d3);

        // butterfly reduce across the 16-lane group; all lanes end with totals
        #pragma unroll
        for (int m = 1; m < 16; m <<= 1) {
            s00 += __shfl_xor(s00, m);
            s11 += __shfl_xor(s11, m);
            s22 += __shfl_xor(s22, m);
            s33 += __shfl_xor(s33, m);
            s01 += __shfl_xor(s01, m);
            s02 += __shfl_xor(s02, m);
            s03 += __shfl_xor(s03, m);
            s12 += __shfl_xor(s12, m);
            s13 += __shfl_xor(s13, m);
            s23 += __shfl_xor(s23, m);
        }

        // lanes 0..3 of each group each compute one row's loss (NEG_IDX):
        //   row0: pos=v02 negs v01,v03 | row1: pos=v13 negs v01,v12
        //   row2: pos=v02 negs v12,v23 | row3: pos=v13 negs v03,v23
        float rl = 0.0f;
        if (lane < 4) {
            const int r = lane;
            float i0 = __frsqrt_rn(fmaxf(s00, EPS*EPS));
            float i1 = __frsqrt_rn(fmaxf(s11, EPS*EPS));
            float i2 = __frsqrt_rn(fmaxf(s22, EPS*EPS));
            float i3 = __frsqrt_rn(fmaxf(s33, EPS*EPS));
            float v01 = s01 * i0 * i1;
            float v02 = s02 * i0 * i2;
            float v03 = s03 * i0 * i3;
            float v12 = s12 * i1 * i2;
            float v13 = s13 * i1 * i3;
            float v23 = s23 * i2 * i3;
            float pos = (r & 1) ? v13 : v02;
            float na  = (r < 2) ? v01 : ((r == 2) ? v12 : v03);
            float nb  = (r == 0) ? v03 : ((r == 1) ? v12 : v23);
            rl = row_loss(pos, na, nb);
        }
        // fold the 4 row losses (stays within lanes 0-3 of the group)
        rl += __shfl_xor(rl, 1);
        rl += __shfl_xor(rl, 2);
        if (lane == 0) local = rl;
    }

    // block reduction: wave64 butterfly, then tiny LDS combine
    #pragma unroll
    for (int m = 1; m < 64; m <<= 1) local += __shfl_xor(local, m);
    __shared__ float red[4];
    if ((threadIdx.x & 63) == 0) red[threadIdx.x >> 6] = local;
    __syncthreads();
    if (threadIdx.x == 0)
        partial[blockIdx.x] = (red[0] + red[1] + red[2] + red[3]) * scale;
}

__global__ __launch_bounds__(256) void ntxent_final_kernel(
    const float* __restrict__ partial, int nb, float* __restrict__ out)
{
    float v = 0.0f;
    for (int i = threadIdx.x; i < nb; i += 256) v += partial[i];
    #pragma unroll
    for (int m = 1; m < 64; m <<= 1) v += __shfl_xor(v, m);
    __shared__ float red[4];
    if ((threadIdx.x & 63) == 0) red[threadIdx.x >> 6] = v;
    __syncthreads();
    if (threadIdx.x == 0) out[0] = red[0] + red[1] + red[2] + red[3];
}

extern "C" void kernel_launch(void* const* d_in, const int* in_sizes, int n_in,
                              void* d_out, int out_size, void* d_ws, size_t ws_size,
                              hipStream_t stream) {
    const float* zis = (const float*)d_in[0];
    const float* zjs = (const float*)d_in[1];
    float* out       = (float*)d_out;
    float* partial   = (float*)d_ws;

    const int B        = in_sizes[0] / D;   // 65536 rows
    const int n_chunks = B / 2;             // 32768 chunks

    int nb = (n_chunks * 16 + 255) / 256;   // 2048 blocks: one 16-lane group per chunk
    size_t cap = ws_size / sizeof(float);
    if (cap < (size_t)nb) nb = (int)(cap > 0 ? cap : 1);

    ntxent_partial_kernel<<<nb, 256, 0, stream>>>(zis, zjs, n_chunks, partial,
                                                  1.0f / (float)B);
    ntxent_final_kernel<<<1, 256, 0, stream>>>(partial, nb, out);
}